// Round 2
// baseline (602.134 us; speedup 1.0000x reference)
//
#include <hip/hip_runtime.h>
#include <hip/hip_bf16.h>
#include <cstdint>
#include <cstddef>

// MotionNet decoder: B=16384, STATE=524, IENC=256, ZD=32, H=256, E=5, HG=256
// Round 8: counted-vmcnt pipelines (T3+T4). __syncthreads drains vmcnt(0),
// killing round-7's issue-early (loads for t+1 were drained at the same
// step's barrier). Now: 3 LDS buffers, raw s_barrier pairs, s_waitcnt
// vmcnt(2c) so tile t's DMAs get ~2 compute iterations of cover. moe_gemm
// upsized to 512 thr / BM=256 (8 waves 4Mx2N, acc[5][4][2]) -> 2x MFMA per
// staged byte, grid = exactly 1 block/CU for l1/l2. setprio(1) around MFMAs.

#define BATCH 16384

typedef __attribute__((ext_vector_type(8))) short short8;  // 8 bf16 (4 VGPRs)
typedef __attribute__((ext_vector_type(4))) float f32x4;   // MFMA accumulator
typedef unsigned short u16;
typedef unsigned int u32;

typedef __attribute__((address_space(3))) void lds_t;
typedef __attribute__((address_space(1))) void gmem_t;

// async global->LDS DMA, 16 B/lane. LDS dest = wave-uniform base + lane*16.
__device__ __forceinline__ void gload16(const u16* g, u16* l) {
  __builtin_amdgcn_global_load_lds((gmem_t*)(u16*)g, (lds_t*)l, 16, 0, 0);
}

// raw workgroup barrier with compiler-only memory fences (no counter drain)
__device__ __forceinline__ void barrier_nodrain() {
  asm volatile("" ::: "memory");
  __builtin_amdgcn_s_barrier();
  asm volatile("" ::: "memory");
}

__device__ __forceinline__ float bf2f(u16 u) {
  union { float f; u32 i; } v; v.i = ((u32)u) << 16; return v.f;
}
__device__ __forceinline__ u16 f2bf(float f) {
  union { float f; u32 i; } v; v.f = f;
  u32 x = v.i;
  return (u16)((x + 0x7fffu + ((x >> 16) & 1u)) >> 16);  // RNE
}
__device__ __forceinline__ u16 load_bf(const void* p, long i, int f32) {
  return f32 ? f2bf(((const float*)p)[i]) : ((const u16*)p)[i];
}
__device__ __forceinline__ float elu_f(float x) { return x > 0.f ? x : expm1f(x); }

// LDS tile layout (validated round 4): rows of 32 u16 (64 B); 16B chunk q of
// row r lives at chunk slot q^((r>>1)&3). Staging lane l covers global chunk
// (l&3)^((l>>3)&3) of row seg+(l>>2); DMA lands it at base + l*16B = correct.
__device__ __forceinline__ int swz(int row, int q) { return q ^ ((row >> 1) & 3); }

// ---------------------------------------------------------------------------
// dtype detection: bf16-pair storage -> word bits 7..14 = low element's
// exponent (near 127 for N(0,1)); fp32 -> uniform mantissa bits.
// flag: 1 = fp32 storage, 0 = bf16 storage.
// ---------------------------------------------------------------------------
__global__ __launch_bounds__(256) void detect_dtype(const u32* __restrict__ zr,
                                                    int* __restrict__ flag)
{
  __shared__ int cnt;
  if (threadIdx.x == 0) cnt = 0;
  __syncthreads();
  u32 w = zr[threadIdx.x];
  int e = (w >> 7) & 0xFF;
  if (e >= 112 && e <= 142) atomicAdd(&cnt, 1);
  __syncthreads();
  if (threadIdx.x == 0) *flag = (cnt < 128) ? 1 : 0;
}

// ---------------------------------------------------------------------------
// prep: h0[B,832] = [z(32) | p_prev(524) | (ienc by inet3) | 0-pad(20)]
//       h1c/h2c[B,288] cols 0..31 = z.  2-D grid: y=row, x*256+tid=col.
// Block (0,0) also canonicalizes small tensors into smallc.
// ---------------------------------------------------------------------------
__global__ __launch_bounds__(256) void prep_kernel(
    const void* __restrict__ z, const void* __restrict__ p,
    const int* __restrict__ flagp,
    u16* __restrict__ h0, u16* __restrict__ h1c, u16* __restrict__ h2c,
    const void* ib1, const void* ib2, const void* ib3,
    const void* gb1, const void* gb2, const void* gb3,
    const void* gw3, const void* bl1, const void* bl2, const void* bl3,
    u16* __restrict__ smallc)
{
  const int f32 = *flagp;
  const int b = blockIdx.y;
  const int c = blockIdx.x * 256 + threadIdx.x;
  if (blockIdx.y == 0 && blockIdx.x == 0) {
    for (long j = threadIdx.x; j < 7100; j += 256) {
      u16 v;
      if      (j < 256)  v = load_bf(ib1, j,        f32);
      else if (j < 512)  v = load_bf(ib2, j - 256,  f32);
      else if (j < 768)  v = load_bf(ib3, j - 512,  f32);
      else if (j < 1024) v = load_bf(gb1, j - 768,  f32);
      else if (j < 1152) v = load_bf(gb2, j - 1024, f32);
      else if (j < 1280) v = (j - 1152 < 5) ? load_bf(gb3, j - 1152, f32) : (u16)0;
      else if (j < 1920) v = load_bf(gw3, j - 1280, f32);
      else if (j < 3200) v = load_bf(bl1, j - 1920, f32);
      else if (j < 4480) v = load_bf(bl2, j - 3200, f32);
      else               v = load_bf(bl3, j - 4480, f32);
      smallc[j] = v;
    }
  }
  if (c >= 832) return;
  const long i = (long)b * 832 + c;
  if (c < 32) {
    u16 v = load_bf(z, (long)b * 32 + c, f32);
    h0[i] = v;
    h1c[(long)b * 288 + c] = v;
    h2c[(long)b * 288 + c] = v;
  } else if (c < 556) {
    h0[i] = load_bf(p, (long)b * 524 + (c - 32), f32);
  } else if (c >= 812) {
    h0[i] = 0;
  }
}

// ---------------------------------------------------------------------------
// I[B,2048] -> canonical bf16, 8 elements/thread
// ---------------------------------------------------------------------------
__global__ __launch_bounds__(256) void convert_I(
    const void* __restrict__ I, const int* __restrict__ flagp,
    u16* __restrict__ out)
{
  const int f32 = *flagp;
  const long total8 = (long)BATCH * 2048 / 8;
  const long stride = (long)gridDim.x * blockDim.x;
  for (long t = (long)blockIdx.x * blockDim.x + threadIdx.x; t < total8; t += stride) {
    if (f32) {
      const float4* src = (const float4*)I;
      float4 a = src[t * 2], b = src[t * 2 + 1];
      union { u16 r[8]; uint4 v; } u;
      u.r[0] = f2bf(a.x); u.r[1] = f2bf(a.y); u.r[2] = f2bf(a.z); u.r[3] = f2bf(a.w);
      u.r[4] = f2bf(b.x); u.r[5] = f2bf(b.y); u.r[6] = f2bf(b.z); u.r[7] = f2bf(b.w);
      *(uint4*)(out + t * 8) = u.v;
    } else {
      *(uint4*)(out + t * 8) = ((const uint4*)I)[t];
    }
  }
}

// ---------------------------------------------------------------------------
// All 8 weight transposes fused: out[e][n][k] = in[e][k][n] or 0-pad.
// ---------------------------------------------------------------------------
struct TPSeg { long end; int K, N, Kp, Np; };

__global__ __launch_bounds__(256) void transpose_all(
    const int* __restrict__ flagp,
    const void* s0, const void* s1, const void* s2, const void* s3,
    const void* s4, const void* s5, const void* s6, const void* s7,
    u16* d0, u16* d1, u16* d2, u16* d3, u16* d4, u16* d5, u16* d6, u16* d7)
{
  const TPSeg seg[8] = {
    {  524288, 2048, 256, 2048, 256 },
    {  589824,  256, 256,  256, 256 },
    {  655360,  256, 256,  256, 256 },
    {  802816,  556, 256,  576, 256 },
    {  835584,  256, 128,  256, 128 },
    { 1900544,  812, 256,  832, 256 },   // E=5
    { 2269184,  288, 256,  288, 256 },   // E=5
    { 3098624,  288, 524,  288, 576 },   // E=5
  };
  const void* const srcs[8] = { s0, s1, s2, s3, s4, s5, s6, s7 };
  u16* const dsts[8] = { d0, d1, d2, d3, d4, d5, d6, d7 };
  const int f32 = *flagp;
  const long total = 3098624;
  const long stride = (long)gridDim.x * blockDim.x;
  for (long i = (long)blockIdx.x * blockDim.x + threadIdx.x; i < total; i += stride) {
    int s = 0;
    long base = 0;
    while (i >= seg[s].end) { base = seg[s].end; ++s; }
    const long j = i - base;
    const int Kp = seg[s].Kp, Np = seg[s].Np, K = seg[s].K, N = seg[s].N;
    const int k = (int)(j % Kp);
    const long t = j / Kp;
    const int n = (int)(t % Np);
    const int e = (int)(t / Np);
    u16 v = 0;
    if (k < K && n < N) v = load_bf(srcs[s], (long)e * K * N + (long)k * N + n, f32);
    dsts[s][j] = v;
  }
}

// ---------------------------------------------------------------------------
// Generic GEMM, round-8: C[M,N] = elu(A[M,K] @ W[K,N] + bias), W [N][K].
// Block 64x128, 4 waves 2(M)x2(N), wave tile 32x64 = 2x4 MFMA 16x16x32.
// 3 LDS buffers, depth-2 prefetch with counted vmcnt (never 0 mid-loop):
//   barrier -> stage(t+2) -> s_waitcnt vmcnt(6) -> barrier -> ds_read+MFMA
// Two raw barriers per step: #1 = WAR (slot t-1 reuse), #2 = publish all
// waves' tile-t DMAs (vmcnt is per-wave!). c=3 DMA instr/wave/stage.
// LDS 36 KB -> 2 blocks/CU.
// ---------------------------------------------------------------------------
template<bool ELU>
__global__ __launch_bounds__(256, 2) void gemm64(
    const u16* __restrict__ A, int lda,
    const u16* __restrict__ Wt, int ldw,
    const u16* __restrict__ bias,
    u16* __restrict__ C, int ldc, int col_off, int K)
{
  __shared__ __align__(16) u16 sA[3][64 * 32];    // 4 KB each
  __shared__ __align__(16) u16 sB[3][128 * 32];   // 8 KB each

  const int tid  = threadIdx.x;
  const int bm   = blockIdx.x, bn = blockIdx.y;
  const int lane = tid & 63, wave = tid >> 6;
  const int wm = (wave & 1) * 32, wn = (wave >> 1) * 64;
  const int lrow = lane & 15, lq = lane >> 4;

  // staging: A rows 16/wave (1 DMA), B rows 32/wave (2 DMAs)
  const int sq    = (lane & 3) ^ ((lane >> 3) & 3);
  const int srowA = 16 * wave + (lane >> 2);
  const int srowB = 32 * wave + (lane >> 2);
  const u16* Ag = A  + (size_t)(bm * 64  + srowA) * lda + sq * 8;
  const u16* Wg = Wt + (size_t)(bn * 128 + srowB) * ldw + sq * 8;
  const int laOff = wave * 512;    // 16 rows * 32 u16
  const int lbOff = wave * 1024;   // 32 rows * 32 u16

  f32x4 acc[2][4] = {};
  const int nt = K / 32;

  // prologue: stage tiles 0 and 1, full drain once
  gload16(Ag, sA[0] + laOff);
  gload16(Wg, sB[0] + lbOff);
  gload16(Wg + (size_t)16 * ldw, sB[0] + lbOff + 512);
  gload16(Ag + 32, sA[1] + laOff);
  gload16(Wg + 32, sB[1] + lbOff);
  gload16(Wg + (size_t)16 * ldw + 32, sB[1] + lbOff + 512);
  __syncthreads();

  for (int t = 0; t < nt; ++t) {
    const int cur = t % 3;
    barrier_nodrain();                       // slot (t+2)%3 == (t-1)%3 free
    if (t + 2 < nt) {
      const int nb = (t + 2) % 3;
      const int k0 = (t + 2) * 32;
      gload16(Ag + k0, sA[nb] + laOff);
      gload16(Wg + k0, sB[nb] + lbOff);
      gload16(Wg + (size_t)16 * ldw + k0, sB[nb] + lbOff + 512);
    }
    const int ahead = nt - 1 - t;
    if (ahead >= 2)      asm volatile("s_waitcnt vmcnt(6)" ::: "memory");
    else if (ahead == 1) asm volatile("s_waitcnt vmcnt(3)" ::: "memory");
    else                 asm volatile("s_waitcnt vmcnt(0)" ::: "memory");
    barrier_nodrain();                       // all waves' tile-t DMAs visible

    short8 a[2], b[4];
#pragma unroll
    for (int i = 0; i < 2; ++i) {
      const int r = wm + i * 16 + lrow;
      a[i] = *(const short8*)(sA[cur] + r * 32 + swz(r, lq) * 8);
    }
#pragma unroll
    for (int i = 0; i < 4; ++i) {
      const int r = wn + i * 16 + lrow;
      b[i] = *(const short8*)(sB[cur] + r * 32 + swz(r, lq) * 8);
    }

    __builtin_amdgcn_s_setprio(1);
#pragma unroll
    for (int mi = 0; mi < 2; ++mi)
#pragma unroll
      for (int ni = 0; ni < 4; ++ni)
        acc[mi][ni] = __builtin_amdgcn_mfma_f32_16x16x32_bf16(a[mi], b[ni], acc[mi][ni], 0, 0, 0);
    __builtin_amdgcn_s_setprio(0);
  }

#pragma unroll
  for (int ni = 0; ni < 4; ++ni) {
    const int col = bn * 128 + wn + ni * 16 + lrow;
    const float bv = bf2f(bias[col]);
#pragma unroll
    for (int mi = 0; mi < 2; ++mi) {
#pragma unroll
      for (int r = 0; r < 4; ++r) {
        const int row = bm * 64 + wm + mi * 16 + lq * 4 + r;
        float v = acc[mi][ni][r] + bv;
        if (ELU) v = elu_f(v);
        C[(size_t)row * ldc + col_off + col] = f2bf(v);
      }
    }
  }
}

// ---------------------------------------------------------------------------
// gating layer 3 + softmax: omega[B,5] fp32 = softmax(g2[B,128]@gw3 + gb3)
// ---------------------------------------------------------------------------
__global__ __launch_bounds__(256) void gating3_kernel(
    const u16* __restrict__ g2, const u16* __restrict__ gw3c,
    const u16* __restrict__ gb3c, float* __restrict__ omega)
{
  const int wid  = (blockIdx.x << 2) + (threadIdx.x >> 6);
  const int lane = threadIdx.x & 63;
  const u32 gp = *(const u32*)(g2 + (size_t)wid * 128 + lane * 2);
  const float x0 = bf2f((u16)(gp & 0xffffu));
  const float x1 = bf2f((u16)(gp >> 16));
  float acc[5];
#pragma unroll
  for (int e = 0; e < 5; ++e)
    acc[e] = x0 * bf2f(gw3c[(lane * 2) * 5 + e]) + x1 * bf2f(gw3c[(lane * 2 + 1) * 5 + e]);
#pragma unroll
  for (int off = 1; off < 64; off <<= 1) {
#pragma unroll
    for (int e = 0; e < 5; ++e) acc[e] += __shfl_xor(acc[e], off);
  }
  if (lane == 0) {
    float t[5], m = -1e30f;
#pragma unroll
    for (int e = 0; e < 5; ++e) { t[e] = acc[e] + bf2f(gb3c[e]); m = fmaxf(m, t[e]); }
    float s = 0.f;
#pragma unroll
    for (int e = 0; e < 5; ++e) { t[e] = expf(t[e] - m); s += t[e]; }
    const float inv = 1.f / s;
#pragma unroll
    for (int e = 0; e < 5; ++e) omega[(size_t)wid * 5 + e] = t[e] * inv;
  }
}

// ---------------------------------------------------------------------------
// MoE GEMM, round-8: out[b,n] = act( sum_e omega[b,e]*((A@W_e)[n]+bias_e[n]) )
// 512 threads, 8 waves as 4(M)x2(N); block tile 256x64, wave tile 64x32:
// per expert 4x2 MFMA -> acc[5][4][2] = 160 VGPR. 3 LDS buffers
// (A 16KB + W 20KB each) + om/bias = ~115 KB -> 1 block/CU, 2 waves/SIMD.
// Staging roles: waves 0-3 stage A (4 DMA), waves 4-7 stage W (5 DMA);
// counted vmcnt per role, two raw barriers per K-step (see gemm64).
// ---------------------------------------------------------------------------
template<bool ELU>
__global__ __launch_bounds__(512, 2) void moe_gemm(
    const u16* __restrict__ A, int lda,
    const u16* __restrict__ Wt, int ldw, long wstride_e,
    const u16* __restrict__ bias, int bias_n,
    const float* __restrict__ omega,
    void* __restrict__ C, int ldc, int col_off, int n_store, int K,
    const int* __restrict__ flagp, int is_final)
{
  __shared__ __align__(16) u16 sA[3][256 * 32];     // 16 KB each
  __shared__ __align__(16) u16 sW[3][5 * 64 * 32];  // 20 KB each
  __shared__ float som[256 * 5];
  __shared__ float sbias[5][64];

  const int tid  = threadIdx.x;
  const int bm   = blockIdx.x, bn = blockIdx.y;
  const int lane = tid & 63, wave = tid >> 6;
  const int wm = (wave & 3) * 64, wn = (wave >> 2) * 32;
  const int lrow = lane & 15, lq = lane >> 4;
  const int f32out = is_final ? *flagp : 0;

  const int sq = (lane & 3) ^ ((lane >> 3) & 3);
  const int isA = (wave < 4);

  // per-wave staging descriptors (all indices static under unroll)
  const u16* gp[5];
  int ldst[5];
  if (isA) {
    // wave w covers A rows 64w+16j .. +15 (j=0..3)
#pragma unroll
    for (int j = 0; j < 4; ++j) {
      const int row = 64 * wave + 16 * j + (lane >> 2);
      gp[j] = A + (size_t)(bm * 256 + row) * lda + sq * 8;
      ldst[j] = wave * 2048 + j * 512;             // u16 offset in sA buffer
    }
    gp[4] = gp[0]; ldst[4] = ldst[0];              // unused
  } else {
    // flat slice d = 5*(w-4)+j in [0,20): expert e=d>>2, rows 16*(d&3)..+15
#pragma unroll
    for (int j = 0; j < 5; ++j) {
      const int d = 5 * (wave - 4) + j;
      const int e = d >> 2, s = d & 3;
      const int row = 16 * s + (lane >> 2);
      gp[j] = Wt + (size_t)e * wstride_e + (size_t)(bn * 64 + row) * ldw + sq * 8;
      ldst[j] = d * 512;                           // u16 offset in sW buffer
    }
  }

  auto stage = [&](int buf, int k0) {
    if (isA) {
#pragma unroll
      for (int j = 0; j < 4; ++j) gload16(gp[j] + k0, sA[buf] + ldst[j]);
    } else {
#pragma unroll
      for (int j = 0; j < 5; ++j) gload16(gp[j] + k0, sW[buf] + ldst[j]);
    }
  };

  f32x4 acc[5][4][2] = {};
  const int nt = K / 32;

  // prologue: stage tiles 0,1; fill omega/bias LDS; full drain once
  stage(0, 0);
  stage(1, 32);
  for (int t2 = tid; t2 < 1600; t2 += 512) {   // 1280 som + 320 sbias
    if (t2 < 1280) {
      som[t2] = omega[(size_t)(bm * 256) * 5 + t2];
    } else {
      const int j = t2 - 1280;
      const int e = j >> 6, c = j & 63;
      const int col = bn * 64 + c;
      sbias[e][c] = (col < bias_n) ? bf2f(bias[(size_t)e * bias_n + col]) : 0.f;
    }
  }
  __syncthreads();

  for (int t = 0; t < nt; ++t) {
    const int cur = t % 3;
    barrier_nodrain();                       // slot (t+2)%3 == (t-1)%3 free
    if (t + 2 < nt) stage((t + 2) % 3, (t + 2) * 32);
    const int ahead = nt - 1 - t;
    if (isA) {
      if (ahead >= 2)      asm volatile("s_waitcnt vmcnt(8)"  ::: "memory");
      else if (ahead == 1) asm volatile("s_waitcnt vmcnt(4)"  ::: "memory");
      else                 asm volatile("s_waitcnt vmcnt(0)"  ::: "memory");
    } else {
      if (ahead >= 2)      asm volatile("s_waitcnt vmcnt(10)" ::: "memory");
      else if (ahead == 1) asm volatile("s_waitcnt vmcnt(5)"  ::: "memory");
      else                 asm volatile("s_waitcnt vmcnt(0)"  ::: "memory");
    }
    barrier_nodrain();                       // all waves' tile-t DMAs visible

    short8 a[4];
#pragma unroll
    for (int i = 0; i < 4; ++i) {
      const int r = wm + i * 16 + lrow;
      a[i] = *(const short8*)(sA[cur] + r * 32 + swz(r, lq) * 8);
    }
    const int rb0 = wn + lrow, rb1 = rb0 + 16;
    const int ob0 = rb0 * 32 + swz(rb0, lq) * 8;
    const int ob1 = rb1 * 32 + swz(rb1, lq) * 8;
    __builtin_amdgcn_s_setprio(1);
#pragma unroll
    for (int e = 0; e < 5; ++e) {
      short8 b0 = *(const short8*)(sW[cur] + e * 2048 + ob0);
      short8 b1 = *(const short8*)(sW[cur] + e * 2048 + ob1);
#pragma unroll
      for (int mi = 0; mi < 4; ++mi) {
        acc[e][mi][0] = __builtin_amdgcn_mfma_f32_16x16x32_bf16(a[mi], b0, acc[e][mi][0], 0, 0, 0);
        acc[e][mi][1] = __builtin_amdgcn_mfma_f32_16x16x32_bf16(a[mi], b1, acc[e][mi][1], 0, 0, 0);
      }
    }
    __builtin_amdgcn_s_setprio(0);
  }

#pragma unroll
  for (int mi = 0; mi < 4; ++mi) {
#pragma unroll
    for (int r = 0; r < 4; ++r) {
      const int rl = wm + mi * 16 + lq * 4 + r;       // row in block tile
      const int row = bm * 256 + rl;
      float om[5];
#pragma unroll
      for (int e = 0; e < 5; ++e) om[e] = som[rl * 5 + e];
#pragma unroll
      for (int ni = 0; ni < 2; ++ni) {
        const int c = wn + ni * 16 + lrow;            // col in block tile
        const int col = bn * 64 + c;
        if (col < n_store) {
          float v = 0.f;
#pragma unroll
          for (int e = 0; e < 5; ++e) v += om[e] * (acc[e][mi][ni][r] + sbias[e][c]);
          if (ELU) v = elu_f(v);
          const size_t idx = (size_t)row * ldc + col_off + col;
          if (f32out) ((float*)C)[idx] = v;
          else        ((u16*)C)[idx]   = f2bf(v);
        }
      }
    }
  }
}

// ---------------------------------------------------------------------------
extern "C" void kernel_launch(void* const* d_in, const int* in_sizes, int n_in,
                              void* d_out, int out_size, void* d_ws, size_t ws_size,
                              hipStream_t stream)
{
  const void* z    = d_in[0];
  const void* pprev= d_in[1];
  const void* I    = d_in[2];
  const void* gw1  = d_in[3];
  const void* gb1  = d_in[4];
  const void* gw2  = d_in[5];
  const void* gb2  = d_in[6];
  const void* gw3  = d_in[7];
  const void* gb3  = d_in[8];
  const void* iw1  = d_in[9];
  const void* ib1  = d_in[10];
  const void* iw2  = d_in[11];
  const void* ib2  = d_in[12];
  const void* iw3  = d_in[13];
  const void* ib3  = d_in[14];
  const void* wl1  = d_in[15];
  const void* bl1  = d_in[16];
  const void* wl2  = d_in[17];
  const void* bl2  = d_in[18];
  const void* wl3  = d_in[19];
  const void* bl3  = d_in[20];

  char* base = (char*)d_ws;
  size_t off = 0;
  auto alloc = [&](size_t bytes) -> void* {
    void* p = base + off;
    off = (off + bytes + 255) & ~(size_t)255;
    return p;
  };

  const size_t B = BATCH;
  int* flagp   = (int*)alloc(256);
  u16* h0      = (u16*)alloc(B * 832 * 2);   // [z | p_prev | ienc | pad0]
  u16* h1c     = (u16*)alloc(B * 288 * 2);   // [z | h1]
  u16* h2c     = (u16*)alloc(B * 288 * 2);   // [z | h2]
  u16* i1      = (u16*)alloc(B * 256 * 2);
  u16* i2      = (u16*)alloc(B * 256 * 2);
  float* omega = (float*)alloc(B * 5 * 4);
  u16* Ibf     = (u16*)alloc(B * 2048 * 2);
  u16* smallc  = (u16*)alloc(7100 * 2);
  u16* iw1t = (u16*)alloc((size_t)256 * 2048 * 2);
  u16* iw2t = (u16*)alloc((size_t)256 * 256 * 2);
  u16* iw3t = (u16*)alloc((size_t)256 * 256 * 2);
  u16* gw1t = (u16*)alloc((size_t)256 * 576 * 2);
  u16* gw2t = (u16*)alloc((size_t)128 * 256 * 2);
  u16* wl1t = (u16*)alloc((size_t)5 * 256 * 832 * 2);
  u16* wl2t = (u16*)alloc((size_t)5 * 256 * 288 * 2);
  u16* wl3t = (u16*)alloc((size_t)5 * 576 * 288 * 2);
  u16* g1 = i1;  // INet temporaries dead by gating time
  u16* g2 = i2;
  (void)in_sizes; (void)n_in; (void)out_size; (void)ws_size;

  u16* ib1c = smallc + 0,   *ib2c = smallc + 256, *ib3c = smallc + 512;
  u16* gb1c = smallc + 768, *gb2c = smallc + 1024, *gb3c = smallc + 1152;
  u16* gw3c = smallc + 1280;
  u16* bl1c = smallc + 1920, *bl2c = smallc + 3200, *bl3c = smallc + 4480;

  // ---- dtype detect + canonicalize ----
  detect_dtype<<<1, 256, 0, stream>>>((const u32*)z, flagp);
  prep_kernel<<<dim3(4, BATCH), 256, 0, stream>>>(z, pprev, flagp, h0, h1c, h2c,
      ib1, ib2, ib3, gb1, gb2, gb3, gw3, bl1, bl2, bl3, smallc);
  convert_I<<<4096, 256, 0, stream>>>(I, flagp, Ibf);
  transpose_all<<<3072, 256, 0, stream>>>(flagp,
      iw1, iw2, iw3, gw1, gw2, wl1, wl2, wl3,
      iw1t, iw2t, iw3t, gw1t, gw2t, wl1t, wl2t, wl3t);

  // ---- INet: I(2048) -> 256 -> 256 -> 256, into h0 cols 556..811 ----
  gemm64<true><<<dim3(BATCH/64, 2), 256, 0, stream>>>(Ibf, 2048, iw1t, 2048, ib1c, i1, 256, 0,   2048);
  gemm64<true><<<dim3(BATCH/64, 2), 256, 0, stream>>>(i1,  256,  iw2t, 256,  ib2c, i2, 256, 0,   256);
  gemm64<true><<<dim3(BATCH/64, 2), 256, 0, stream>>>(i2,  256,  iw3t, 256,  ib3c, h0, 832, 556, 256);

  // ---- Gating: [z|p_prev](556, padded 576) -> 256 -> 128 -> softmax(5) ----
  gemm64<true><<<dim3(BATCH/64, 2), 256, 0, stream>>>(h0, 832, gw1t, 576, gb1c, g1, 256, 0, 576);
  gemm64<true><<<dim3(BATCH/64, 1), 256, 0, stream>>>(g1, 256, gw2t, 256, gb2c, g2, 128, 0, 256);
  gating3_kernel<<<BATCH/4, 256, 0, stream>>>(g2, gw3c, gb3c, omega);

  // ---- MoE layers (block 256x64, 512 thr, counted-vmcnt pipeline) ----
  moe_gemm<true><<<dim3(BATCH/256, 4), 512, 0, stream>>>(
      h0, 832, wl1t, 832, (long)256 * 832, bl1c, 256, omega, h1c, 288, 32, 256, 832, flagp, 0);
  moe_gemm<true><<<dim3(BATCH/256, 4), 512, 0, stream>>>(
      h1c, 288, wl2t, 288, (long)256 * 288, bl2c, 256, omega, h2c, 288, 32, 256, 288, flagp, 0);
  moe_gemm<false><<<dim3(BATCH/256, 9), 512, 0, stream>>>(
      h2c, 288, wl3t, 288, (long)576 * 288, bl3c, 524, omega, d_out, 524, 0, 524, 288, flagp, 1);
}

// Round 3
// 515.117 us; speedup vs baseline: 1.1689x; 1.1689x over previous
//
#include <hip/hip_runtime.h>
#include <hip/hip_bf16.h>
#include <cstdint>
#include <cstddef>

// MotionNet decoder: B=16384, STATE=524, IENC=256, ZD=32, H=256, E=5, HG=256
// Round 9: occupancy + serialization attack.
//  - moe_gemm back to 256-thr/128x64 (r8's 512-thr/115KB-LDS was 1 block/CU =
//    the m132 failure mode), with depth-1 counted-vmcnt pipeline (2 buffers,
//    56KB, 2 blocks/CU): barrier -> stage(t+1) -> vmcnt(7) -> barrier -> MFMA.
//  - small GEMMs horizontally fused via GemmDesc multi-kernel:
//    [inet1|gat1], [inet2|gat2], [inet3]  (g1/g2 un-aliased from i1/i2).
//  - prep/convert_I/transpose/dtype-detect fused into one grid-stride kernel;
//    gating3+softmax folded into moe prologue (per-block omega from g2).
//  11 launches -> 7.

#define BATCH 16384

typedef __attribute__((ext_vector_type(8))) short short8;  // 8 bf16 (4 VGPRs)
typedef __attribute__((ext_vector_type(4))) float f32x4;   // MFMA accumulator
typedef unsigned short u16;
typedef unsigned int u32;

typedef __attribute__((address_space(3))) void lds_t;
typedef __attribute__((address_space(1))) void gmem_t;

// async global->LDS DMA, 16 B/lane. LDS dest = wave-uniform base + lane*16.
__device__ __forceinline__ void gload16(const u16* g, u16* l) {
  __builtin_amdgcn_global_load_lds((gmem_t*)(u16*)g, (lds_t*)l, 16, 0, 0);
}

// raw workgroup barrier (no counter drain)
__device__ __forceinline__ void barrier_nodrain() {
  asm volatile("" ::: "memory");
  __builtin_amdgcn_s_barrier();
  asm volatile("" ::: "memory");
}
// barrier draining LDS ops only (ds_write visibility) — vmcnt stays in flight
__device__ __forceinline__ void barrier_lds() {
  asm volatile("s_waitcnt lgkmcnt(0)" ::: "memory");
  __builtin_amdgcn_s_barrier();
  asm volatile("" ::: "memory");
}

__device__ __forceinline__ float bf2f(u16 u) {
  union { float f; u32 i; } v; v.i = ((u32)u) << 16; return v.f;
}
__device__ __forceinline__ u16 f2bf(float f) {
  union { float f; u32 i; } v; v.f = f;
  u32 x = v.i;
  return (u16)((x + 0x7fffu + ((x >> 16) & 1u)) >> 16);  // RNE
}
__device__ __forceinline__ u16 load_bf(const void* p, long i, int f32) {
  return f32 ? f2bf(((const float*)p)[i]) : ((const u16*)p)[i];
}
__device__ __forceinline__ float elu_f(float x) { return x > 0.f ? x : expm1f(x); }

// LDS tile layout (validated round 4): rows of 32 u16 (64 B); 16B chunk q of
// row r lives at chunk slot q^((r>>1)&3). Staging lane l covers global chunk
// (l&3)^((l>>3)&3) of row seg+(l>>2); DMA lands it at base + l*16B = correct.
__device__ __forceinline__ int swz(int row, int q) { return q ^ ((row >> 1) & 3); }

// ---------------------------------------------------------------------------
// prep_all: fused {dtype detect (per-block, block 0 publishes flagp),
//   smallc canonicalize (block 0), h0/h1c/h2c build, I->bf16 convert,
//   all 8 weight transposes}. One grid-stride index space, vectorized x4.
// h0 cols 556..811 are ZEROED here (gat1 reads h0[:,0:576] before inet3
// overwrites 556.. — its W rows there are 0-padded, but 0*poison=NaN).
// ---------------------------------------------------------------------------
struct TPSeg { long end; int K, N, Kp, Np; };

__global__ __launch_bounds__(256) void prep_all(
    const void* __restrict__ z, const void* __restrict__ p,
    const void* __restrict__ I, int* __restrict__ flagp,
    u16* __restrict__ h0, u16* __restrict__ h1c, u16* __restrict__ h2c,
    u16* __restrict__ Ibf,
    const void* ib1, const void* ib2, const void* ib3,
    const void* gb1, const void* gb2, const void* gb3,
    const void* gw3, const void* bl1, const void* bl2, const void* bl3,
    u16* __restrict__ smallc,
    const void* s0, const void* s1, const void* s2, const void* s3,
    const void* s4, const void* s5, const void* s6, const void* s7,
    u16* d0, u16* d1, u16* d2, u16* d3, u16* d4, u16* d5, u16* d6, u16* d7)
{
  // ---- per-block dtype detection (no cross-block dependency) ----
  __shared__ int scnt[4];
  {
    u32 w = ((const u32*)z)[threadIdx.x];
    int e = (w >> 7) & 0xFF;
    unsigned long long m = __ballot(e >= 112 && e <= 142);
    if ((threadIdx.x & 63) == 0) scnt[threadIdx.x >> 6] = __popcll(m);
  }
  __syncthreads();
  const int f32 = (scnt[0] + scnt[1] + scnt[2] + scnt[3] < 128) ? 1 : 0;
  if (blockIdx.x == 0 && threadIdx.x == 0) *flagp = f32;

  // ---- block 0: small-tensor canonicalize ----
  if (blockIdx.x == 0) {
    for (long j = threadIdx.x; j < 7100; j += 256) {
      u16 v;
      if      (j < 256)  v = load_bf(ib1, j,        f32);
      else if (j < 512)  v = load_bf(ib2, j - 256,  f32);
      else if (j < 768)  v = load_bf(ib3, j - 512,  f32);
      else if (j < 1024) v = load_bf(gb1, j - 768,  f32);
      else if (j < 1152) v = load_bf(gb2, j - 1024, f32);
      else if (j < 1280) v = (j - 1152 < 5) ? load_bf(gb3, j - 1152, f32) : (u16)0;
      else if (j < 1920) v = load_bf(gw3, j - 1280, f32);
      else if (j < 3200) v = load_bf(bl1, j - 1920, f32);
      else if (j < 4480) v = load_bf(bl2, j - 3200, f32);
      else               v = load_bf(bl3, j - 4480, f32);
      smallc[j] = v;
    }
  }

  const TPSeg seg[8] = {
    {  524288, 2048, 256, 2048, 256 },
    {  589824,  256, 256,  256, 256 },
    {  655360,  256, 256,  256, 256 },
    {  802816,  556, 256,  576, 256 },
    {  835584,  256, 128,  256, 128 },
    { 1900544,  812, 256,  832, 256 },   // E=5
    { 2269184,  288, 256,  288, 256 },   // E=5
    { 3098624,  288, 524,  288, 576 },   // E=5
  };
  const void* const srcs[8] = { s0, s1, s2, s3, s4, s5, s6, s7 };
  u16* const dsts[8] = { d0, d1, d2, d3, d4, d5, d6, d7 };

  const long NC = (long)BATCH * 2048 / 8;   // convert items (8 u16 each)
  const long NP = (long)BATCH * 208;        // prep items (4 cols each)
  const long NT = 774656;                   // transpose items (4 k each)
  const long total = NC + NP + NT;
  const long stride = (long)gridDim.x * blockDim.x;

  for (long it = (long)blockIdx.x * 256 + threadIdx.x; it < total; it += stride) {
    if (it < NC) {
      // ---- I convert ----
      const long t = it;
      if (f32) {
        const float4* src = (const float4*)I;
        float4 a = src[t * 2], b = src[t * 2 + 1];
        union { u16 r[8]; uint4 v; } u;
        u.r[0] = f2bf(a.x); u.r[1] = f2bf(a.y); u.r[2] = f2bf(a.z); u.r[3] = f2bf(a.w);
        u.r[4] = f2bf(b.x); u.r[5] = f2bf(b.y); u.r[6] = f2bf(b.z); u.r[7] = f2bf(b.w);
        *(uint4*)(Ibf + t * 8) = u.v;
      } else {
        *(uint4*)(Ibf + t * 8) = ((const uint4*)I)[t];
      }
    } else if (it < NC + NP) {
      // ---- h0/h1c/h2c build, 4 cols per item (all boundaries %4==0) ----
      const long j = it - NC;
      const int b = (int)(j / 208);
      const int c = (int)(j % 208) * 4;
      ushort4 v;
      if (c < 32) {
        const long zi = (long)b * 32 + c;
        if (f32) {
          const float4 f = *(const float4*)((const float*)z + zi);
          v.x = f2bf(f.x); v.y = f2bf(f.y); v.z = f2bf(f.z); v.w = f2bf(f.w);
        } else {
          v = *(const ushort4*)((const u16*)z + zi);
        }
        *(ushort4*)(h0 + (long)b * 832 + c) = v;
        *(ushort4*)(h1c + (long)b * 288 + c) = v;
        *(ushort4*)(h2c + (long)b * 288 + c) = v;
      } else if (c < 556) {
        const long pi = (long)b * 524 + (c - 32);
        if (f32) {
          const float4 f = *(const float4*)((const float*)p + pi);
          v.x = f2bf(f.x); v.y = f2bf(f.y); v.z = f2bf(f.z); v.w = f2bf(f.w);
        } else {
          v = *(const ushort4*)((const u16*)p + pi);
        }
        *(ushort4*)(h0 + (long)b * 832 + c) = v;
      } else {
        v.x = 0; v.y = 0; v.z = 0; v.w = 0;   // 556..811 zeroed (inet3 fills)
        *(ushort4*)(h0 + (long)b * 832 + c) = v;
      }
    } else {
      // ---- weight transpose, 4 consecutive k per item ----
      const long jd = (it - NC - NP) * 4;
      int s = 0; long sbase = 0;
      while (jd >= seg[s].end) { sbase = seg[s].end; ++s; }
      const long jj = jd - sbase;
      const int Kp = seg[s].Kp, Np = seg[s].Np, Kk = seg[s].K, Nn = seg[s].N;
      const int k = (int)(jj % Kp);
      const long tt = jj / Kp;
      const int n = (int)(tt % Np);
      const int e = (int)(tt / Np);
      ushort4 v; v.x = 0; v.y = 0; v.z = 0; v.w = 0;
      if (k < Kk && n < Nn) {   // Kk,k both %4==0 -> uniform over the 4
        const long sb = (long)e * Kk * Nn + (long)k * Nn + n;
        v.x = load_bf(srcs[s], sb, f32);
        v.y = load_bf(srcs[s], sb + Nn, f32);
        v.z = load_bf(srcs[s], sb + 2 * (long)Nn, f32);
        v.w = load_bf(srcs[s], sb + 3 * (long)Nn, f32);
      }
      *(ushort4*)(dsts[s] + jj) = v;
    }
  }
}

// ---------------------------------------------------------------------------
// Multi-segment GEMM: C = elu(A @ W + bias), W stored [N][K].
// Block 64x128, 4 waves 2(M)x2(N), wave tile 32x64 = 2x4 MFMA 16x16x32.
// 3 LDS buffers, depth-2 counted-vmcnt pipeline (r8 form, validated):
//   barrier -> stage(t+2) -> s_waitcnt vmcnt(6) -> barrier -> ds_read+MFMA
// blockIdx.y selects segment descriptor (horizontal fusion of indep GEMMs).
// ---------------------------------------------------------------------------
struct GemmDesc {
  const u16* A; const u16* Wt; const u16* bias; u16* C;
  int lda, ldw, ldc, col_off, K, ny;
};

__global__ __launch_bounds__(256, 2) void gemm64m(GemmDesc da, GemmDesc db)
{
  __shared__ __align__(16) u16 sA[3][64 * 32];    // 4 KB each
  __shared__ __align__(16) u16 sB[3][128 * 32];   // 8 KB each

  int bn = blockIdx.y;
  GemmDesc d;
  if (bn < da.ny) { d = da; } else { bn -= da.ny; d = db; }

  const int tid  = threadIdx.x;
  const int bm   = blockIdx.x;
  const int lane = tid & 63, wave = tid >> 6;
  const int wm = (wave & 1) * 32, wn = (wave >> 1) * 64;
  const int lrow = lane & 15, lq = lane >> 4;

  // staging: A rows 16/wave (1 DMA), B rows 32/wave (2 DMAs)
  const int sq    = (lane & 3) ^ ((lane >> 3) & 3);
  const int srowA = 16 * wave + (lane >> 2);
  const int srowB = 32 * wave + (lane >> 2);
  const u16* Ag = d.A  + (size_t)(bm * 64  + srowA) * d.lda + sq * 8;
  const u16* Wg = d.Wt + (size_t)(bn * 128 + srowB) * d.ldw + sq * 8;
  const int laOff = wave * 512;    // 16 rows * 32 u16
  const int lbOff = wave * 1024;   // 32 rows * 32 u16
  const int ldw = d.ldw;

  f32x4 acc[2][4] = {};
  const int nt = d.K / 32;

  // prologue: stage tiles 0 and 1 (no drain — loop's vmcnt covers)
  gload16(Ag, sA[0] + laOff);
  gload16(Wg, sB[0] + lbOff);
  gload16(Wg + (size_t)16 * ldw, sB[0] + lbOff + 512);
  gload16(Ag + 32, sA[1] + laOff);
  gload16(Wg + 32, sB[1] + lbOff);
  gload16(Wg + (size_t)16 * ldw + 32, sB[1] + lbOff + 512);

  for (int t = 0; t < nt; ++t) {
    const int cur = t % 3;
    barrier_nodrain();                       // WAR: slot (t+2)%3 free
    if (t + 2 < nt) {
      const int nb = (t + 2) % 3;
      const int k0 = (t + 2) * 32;
      gload16(Ag + k0, sA[nb] + laOff);
      gload16(Wg + k0, sB[nb] + lbOff);
      gload16(Wg + (size_t)16 * ldw + k0, sB[nb] + lbOff + 512);
    }
    const int ahead = nt - 1 - t;
    if (ahead >= 2)      asm volatile("s_waitcnt vmcnt(6)" ::: "memory");
    else if (ahead == 1) asm volatile("s_waitcnt vmcnt(3)" ::: "memory");
    else                 asm volatile("s_waitcnt vmcnt(0)" ::: "memory");
    barrier_nodrain();                       // all waves' tile-t DMAs visible

    short8 a[2], b[4];
#pragma unroll
    for (int i = 0; i < 2; ++i) {
      const int r = wm + i * 16 + lrow;
      a[i] = *(const short8*)(sA[cur] + r * 32 + swz(r, lq) * 8);
    }
#pragma unroll
    for (int i = 0; i < 4; ++i) {
      const int r = wn + i * 16 + lrow;
      b[i] = *(const short8*)(sB[cur] + r * 32 + swz(r, lq) * 8);
    }

    __builtin_amdgcn_s_setprio(1);
#pragma unroll
    for (int mi = 0; mi < 2; ++mi)
#pragma unroll
      for (int ni = 0; ni < 4; ++ni)
        acc[mi][ni] = __builtin_amdgcn_mfma_f32_16x16x32_bf16(a[mi], b[ni], acc[mi][ni], 0, 0, 0);
    __builtin_amdgcn_s_setprio(0);
  }

#pragma unroll
  for (int ni = 0; ni < 4; ++ni) {
    const int col = bn * 128 + wn + ni * 16 + lrow;
    const float bv = bf2f(d.bias[col]);
#pragma unroll
    for (int mi = 0; mi < 2; ++mi) {
#pragma unroll
      for (int r = 0; r < 4; ++r) {
        const int row = bm * 64 + wm + mi * 16 + lq * 4 + r;
        float v = acc[mi][ni][r] + bv;
        v = elu_f(v);
        d.C[(size_t)row * d.ldc + d.col_off + col] = f2bf(v);
      }
    }
  }
}

// ---------------------------------------------------------------------------
// MoE GEMM: out[b,n] = act( sum_e omega[b,e]*((A@W_e)[n]+bias_e[n]) )
// 256 threads, block 128x64, 4 waves 2(M)x2(N), wave tile 64x32:
// per expert 4x2 MFMA -> acc[5][4][2] = 160 VGPR (needs the (256,2) bound).
// Depth-1 counted-vmcnt pipeline, 2 LDS buffers (56KB -> 2 blocks/CU):
//   barrier -> stage(t+1) -> s_waitcnt vmcnt(7) -> barrier -> MFMA
// Gating layer-3 + softmax fused into the prologue: threads 0..127 each
// compute one omega row from g2 (weights staged in LDS), hidden under the
// tile-0 DMA latency. A tile staged once, reused by all 5 experts.
// ---------------------------------------------------------------------------
template<bool ELU>
__global__ __launch_bounds__(256, 2) void moe_gemm(
    const u16* __restrict__ A, int lda,
    const u16* __restrict__ Wt, int ldw, long wstride_e,
    const u16* __restrict__ bias, int bias_n,
    const u16* __restrict__ g2, const u16* __restrict__ gw3c,
    const u16* __restrict__ gb3c,
    void* __restrict__ C, int ldc, int col_off, int n_store, int K,
    const int* __restrict__ flagp, int is_final)
{
  __shared__ __align__(16) u16 sA[2][128 * 32];     // 8 KB each
  __shared__ __align__(16) u16 sW[2][5 * 64 * 32];  // 20 KB each
  __shared__ float som[128 * 5];
  __shared__ float sbias[5][64];
  __shared__ float sgw[128 * 5];
  __shared__ float sgb[5];

  const int tid  = threadIdx.x;
  const int bm   = blockIdx.x, bn = blockIdx.y;
  const int lane = tid & 63, wave = tid >> 6;
  const int wm = (wave & 1) * 64, wn = (wave >> 1) * 32;
  const int lrow = lane & 15, lq = lane >> 4;
  const int f32out = is_final ? *flagp : 0;

  // staging: wave w covers A rows 32w..32w+31 (2 DMAs) and W rows 16w..16w+15
  // of each expert (5 DMAs) = 7 DMAs/wave/tile. Round-4-validated pattern.
  const int sq = (lane & 3) ^ ((lane >> 3) & 3);
  const int srowA = 32 * wave + (lane >> 2);
  const int srowW = 16 * wave + (lane >> 2);
  const u16* Ag = A  + (size_t)(bm * 128 + srowA) * lda + sq * 8;
  const u16* Wg = Wt + (size_t)(bn * 64 + srowW) * ldw + sq * 8;
  const int laOff = wave * 1024;    // 32 rows * 32 u16
  const int lWoff = wave * 512;     // 16 rows * 32 u16

  auto stage = [&](int buf, int k0) {
    gload16(Ag + k0, sA[buf] + laOff);
    gload16(Ag + (size_t)16 * lda + k0, sA[buf] + laOff + 512);
#pragma unroll
    for (int e = 0; e < 5; ++e)
      gload16(Wg + e * wstride_e + k0, sW[buf] + e * 2048 + lWoff);
  };

  f32x4 acc[5][4][2] = {};
  const int nt = K / 32;

  // ---- prologue: tile-0 DMAs in flight while we build omega in-block ----
  stage(0, 0);
  for (int t2 = tid; t2 < 960; t2 += 256) {   // 640 sgw + 320 sbias
    if (t2 < 640) {
      sgw[t2] = bf2f(gw3c[t2]);
    } else {
      const int j = t2 - 640;
      const int e = j >> 6, c = j & 63;
      const int col = bn * 64 + c;
      sbias[e][c] = (col < bias_n) ? bf2f(bias[(size_t)e * bias_n + col]) : 0.f;
    }
  }
  if (tid < 5) sgb[tid] = bf2f(gb3c[tid]);
  barrier_lds();                              // sgw/sgb visible; DMAs still fly
  if (tid < 128) {
    const u16* gr = g2 + (size_t)(bm * 128 + tid) * 128;
    float t[5];
#pragma unroll
    for (int e = 0; e < 5; ++e) t[e] = sgb[e];
    for (int k = 0; k < 128; k += 2) {
      const u32 gp = *(const u32*)(gr + k);
      const float x0 = bf2f((u16)(gp & 0xffffu));
      const float x1 = bf2f((u16)(gp >> 16));
#pragma unroll
      for (int e = 0; e < 5; ++e)
        t[e] += x0 * sgw[k * 5 + e] + x1 * sgw[(k + 1) * 5 + e];
    }
    float m = t[0];
#pragma unroll
    for (int e = 1; e < 5; ++e) m = fmaxf(m, t[e]);
    float ssum = 0.f;
#pragma unroll
    for (int e = 0; e < 5; ++e) { t[e] = expf(t[e] - m); ssum += t[e]; }
    const float inv = 1.f / ssum;
#pragma unroll
    for (int e = 0; e < 5; ++e) som[tid * 5 + e] = t[e] * inv;
  }
  // som visibility: writers drain lgkm before their first MFMA (in-order
  // counter); readers touch som only in the epilogue, nt>=9 barriers later.

  for (int t = 0; t < nt; ++t) {
    const int cur = t & 1;
    barrier_nodrain();                   // WAR: buf[cur^1] free / syncs prologue
    if (t + 1 < nt) {
      stage(cur ^ 1, (t + 1) * 32);
      asm volatile("s_waitcnt vmcnt(7)" ::: "memory");   // tile t landed
    } else {
      asm volatile("s_waitcnt vmcnt(0)" ::: "memory");
    }
    barrier_nodrain();                   // all waves' tile-t DMAs visible

    short8 a[4];
#pragma unroll
    for (int i = 0; i < 4; ++i) {
      const int r = wm + i * 16 + lrow;
      a[i] = *(const short8*)(sA[cur] + r * 32 + swz(r, lq) * 8);
    }
    const int rb0 = wn + lrow, rb1 = rb0 + 16;
    const int ob0 = rb0 * 32 + swz(rb0, lq) * 8;
    const int ob1 = rb1 * 32 + swz(rb1, lq) * 8;
    __builtin_amdgcn_s_setprio(1);
#pragma unroll
    for (int e = 0; e < 5; ++e) {
      short8 b0 = *(const short8*)(sW[cur] + e * 2048 + ob0);
      short8 b1 = *(const short8*)(sW[cur] + e * 2048 + ob1);
#pragma unroll
      for (int mi = 0; mi < 4; ++mi) {
        acc[e][mi][0] = __builtin_amdgcn_mfma_f32_16x16x32_bf16(a[mi], b0, acc[e][mi][0], 0, 0, 0);
        acc[e][mi][1] = __builtin_amdgcn_mfma_f32_16x16x32_bf16(a[mi], b1, acc[e][mi][1], 0, 0, 0);
      }
    }
    __builtin_amdgcn_s_setprio(0);
  }

#pragma unroll
  for (int mi = 0; mi < 4; ++mi) {
#pragma unroll
    for (int r = 0; r < 4; ++r) {
      const int rl = wm + mi * 16 + lq * 4 + r;       // row in block tile
      const int row = bm * 128 + rl;
      float om[5];
#pragma unroll
      for (int e = 0; e < 5; ++e) om[e] = som[rl * 5 + e];
#pragma unroll
      for (int ni = 0; ni < 2; ++ni) {
        const int c = wn + ni * 16 + lrow;            // col in block tile
        const int col = bn * 64 + c;
        if (col < n_store) {
          float v = 0.f;
#pragma unroll
          for (int e = 0; e < 5; ++e) v += om[e] * (acc[e][mi][ni][r] + sbias[e][c]);
          if (ELU) v = elu_f(v);
          const size_t idx = (size_t)row * ldc + col_off + col;
          if (f32out) ((float*)C)[idx] = v;
          else        ((u16*)C)[idx]   = f2bf(v);
        }
      }
    }
  }
}

// ---------------------------------------------------------------------------
extern "C" void kernel_launch(void* const* d_in, const int* in_sizes, int n_in,
                              void* d_out, int out_size, void* d_ws, size_t ws_size,
                              hipStream_t stream)
{
  const void* z    = d_in[0];
  const void* pprev= d_in[1];
  const void* I    = d_in[2];
  const void* gw1  = d_in[3];
  const void* gb1  = d_in[4];
  const void* gw2  = d_in[5];
  const void* gb2  = d_in[6];
  const void* gw3  = d_in[7];
  const void* gb3  = d_in[8];
  const void* iw1  = d_in[9];
  const void* ib1  = d_in[10];
  const void* iw2  = d_in[11];
  const void* ib2  = d_in[12];
  const void* iw3  = d_in[13];
  const void* ib3  = d_in[14];
  const void* wl1  = d_in[15];
  const void* bl1  = d_in[16];
  const void* wl2  = d_in[17];
  const void* bl2  = d_in[18];
  const void* wl3  = d_in[19];
  const void* bl3  = d_in[20];

  char* base = (char*)d_ws;
  size_t off = 0;
  auto alloc = [&](size_t bytes) -> void* {
    void* p = base + off;
    off = (off + bytes + 255) & ~(size_t)255;
    return p;
  };

  const size_t B = BATCH;
  int* flagp   = (int*)alloc(256);
  u16* h0      = (u16*)alloc(B * 832 * 2);   // [z | p_prev | ienc | pad0]
  u16* h1c     = (u16*)alloc(B * 288 * 2);   // [z | h1]
  u16* h2c     = (u16*)alloc(B * 288 * 2);   // [z | h2]
  u16* i1      = (u16*)alloc(B * 256 * 2);
  u16* i2      = (u16*)alloc(B * 256 * 2);
  u16* g1      = (u16*)alloc(B * 256 * 2);   // un-aliased: runs concurrent w/ i1
  u16* g2      = (u16*)alloc(B * 128 * 2);
  u16* Ibf     = (u16*)alloc(B * 2048 * 2);
  u16* smallc  = (u16*)alloc(7100 * 2);
  u16* iw1t = (u16*)alloc((size_t)256 * 2048 * 2);
  u16* iw2t = (u16*)alloc((size_t)256 * 256 * 2);
  u16* iw3t = (u16*)alloc((size_t)256 * 256 * 2);
  u16* gw1t = (u16*)alloc((size_t)256 * 576 * 2);
  u16* gw2t = (u16*)alloc((size_t)128 * 256 * 2);
  u16* wl1t = (u16*)alloc((size_t)5 * 256 * 832 * 2);
  u16* wl2t = (u16*)alloc((size_t)5 * 256 * 288 * 2);
  u16* wl3t = (u16*)alloc((size_t)5 * 576 * 288 * 2);
  (void)in_sizes; (void)n_in; (void)out_size; (void)ws_size;

  u16* ib1c = smallc + 0,   *ib2c = smallc + 256, *ib3c = smallc + 512;
  u16* gb1c = smallc + 768, *gb2c = smallc + 1024, *gb3c = smallc + 1152;
  u16* gw3c = smallc + 1280;
  u16* bl1c = smallc + 1920, *bl2c = smallc + 3200, *bl3c = smallc + 4480;

  // ---- fused prep: dtype detect + canonicalize + convert + transpose ----
  prep_all<<<2048, 256, 0, stream>>>(z, pprev, I, flagp, h0, h1c, h2c, Ibf,
      ib1, ib2, ib3, gb1, gb2, gb3, gw3, bl1, bl2, bl3, smallc,
      iw1, iw2, iw3, gw1, gw2, wl1, wl2, wl3,
      iw1t, iw2t, iw3t, gw1t, gw2t, wl1t, wl2t, wl3t);

  // ---- fused small GEMMs: INet chain || gating chain ----
  GemmDesc inet1 = { Ibf, iw1t, ib1c, i1, 2048, 2048, 256, 0,   2048, 2 };
  GemmDesc gat1  = { h0,  gw1t, gb1c, g1,  832,  576, 256, 0,    576, 2 };
  GemmDesc inet2 = { i1,  iw2t, ib2c, i2,  256,  256, 256, 0,    256, 2 };
  GemmDesc gat2  = { g1,  gw2t, gb2c, g2,  256,  256, 128, 0,    256, 1 };
  GemmDesc inet3 = { i2,  iw3t, ib3c, h0,  256,  256, 832, 556,  256, 2 };

  gemm64m<<<dim3(BATCH/64, 4), 256, 0, stream>>>(inet1, gat1);
  gemm64m<<<dim3(BATCH/64, 3), 256, 0, stream>>>(inet2, gat2);
  gemm64m<<<dim3(BATCH/64, 2), 256, 0, stream>>>(inet3, inet3);

  // ---- MoE layers (block 128x64, depth-1 counted-vmcnt, omega in-block) ----
  moe_gemm<true><<<dim3(BATCH/128, 4), 256, 0, stream>>>(
      h0, 832, wl1t, 832, (long)256 * 832, bl1c, 256, g2, gw3c, gb3c,
      h1c, 288, 32, 256, 832, flagp, 0);
  moe_gemm<true><<<dim3(BATCH/128, 4), 256, 0, stream>>>(
      h1c, 288, wl2t, 288, (long)256 * 288, bl2c, 256, g2, gw3c, gb3c,
      h2c, 288, 32, 256, 288, flagp, 0);
  moe_gemm<false><<<dim3(BATCH/128, 9), 256, 0, stream>>>(
      h2c, 288, wl3t, 288, (long)576 * 288, bl3c, 524, g2, gw3c, gb3c,
      d_out, 524, 0, 524, 288, flagp, 1);
}